// Round 1
// baseline (428.418 us; speedup 1.0000x reference)
//
#include <hip/hip_runtime.h>

#define BS 7
#define DROPP 0.1f
#define H 64
#define W 64
#define UH (H - BS + 1)   // 58
#define UW (W - BS + 1)   // 58

// One block: build mask[64*64], reduce sum, write m = mask*scale to ws.
__global__ __launch_bounds__(1024) void dropblock_mask_kernel(
    const float* __restrict__ u, float* __restrict__ m)
{
    __shared__ float su[UH * UW];   // 3364 floats = 13.5 KiB
    __shared__ float ssum[16];
    __shared__ float sscale;

    const int tid = threadIdx.x;
    for (int i = tid; i < UH * UW; i += 1024) su[i] = u[i];
    __syncthreads();

    float mv[4];
    float local = 0.0f;
    #pragma unroll
    for (int k = 0; k < 4; ++k) {
        const int p = tid * 4 + k;          // pixel index 0..4095
        const int y = p >> 6;
        const int x = p & 63;
        const int i0 = (y - 6 > 0) ? (y - 6) : 0;
        const int i1 = (y < UH - 1) ? y : (UH - 1);
        const int j0 = (x - 6 > 0) ? (x - 6) : 0;
        const int j1 = (x < UW - 1) ? x : (UW - 1);
        float keep = 1.0f;
        for (int i = i0; i <= i1; ++i)
            for (int j = j0; j <= j1; ++j)
                if (su[i * UW + j] < DROPP) keep = 0.0f;
        mv[k] = keep;
        local += keep;
    }

    // wave (64-lane) shuffle reduce, then LDS reduce across 16 waves
    #pragma unroll
    for (int off = 32; off >= 1; off >>= 1)
        local += __shfl_down(local, off, 64);
    const int wave = tid >> 6;
    const int lane = tid & 63;
    if (lane == 0) ssum[wave] = local;
    __syncthreads();
    if (tid == 0) {
        float tot = 0.0f;
        #pragma unroll
        for (int wv = 0; wv < 16; ++wv) tot += ssum[wv];
        sscale = (float)(H * W) / tot;
    }
    __syncthreads();

    const float s = sscale;
    #pragma unroll
    for (int k = 0; k < 4; ++k)
        m[tid * 4 + k] = mv[k] * s;
}

// HBM-bound elementwise: one float4 per lane. m4 (16 KiB) stays cache-resident.
__global__ __launch_bounds__(256) void dropblock_apply_kernel(
    const float4* __restrict__ x, const float* __restrict__ m,
    float4* __restrict__ out)
{
    const int gid = blockIdx.x * 256 + threadIdx.x;
    const float4* m4 = (const float4*)m;
    const float4 xv = x[gid];
    const float4 mv = m4[gid & 1023];   // plane = 4096 floats = 1024 float4s
    float4 ov;
    ov.x = xv.x * mv.x;
    ov.y = xv.y * mv.y;
    ov.z = xv.z * mv.z;
    ov.w = xv.w * mv.w;
    out[gid] = ov;
}

extern "C" void kernel_launch(void* const* d_in, const int* in_sizes, int n_in,
                              void* d_out, int out_size, void* d_ws, size_t ws_size,
                              hipStream_t stream) {
    const float* x = (const float*)d_in[0];   // [64,256,64,64] fp32
    const float* u = (const float*)d_in[1];   // [58,58] fp32
    float* out = (float*)d_out;
    float* m   = (float*)d_ws;                // 4096 floats of scratch

    dropblock_mask_kernel<<<1, 1024, 0, stream>>>(u, m);

    const int total4 = out_size / 4;          // 16,777,216
    dropblock_apply_kernel<<<total4 / 256, 256, 0, stream>>>(
        (const float4*)x, m, (float4*)out);
}

// Round 3
// 416.253 us; speedup vs baseline: 1.0292x; 1.0292x over previous
//
#include <hip/hip_runtime.h>

#define BS 7
#define DROPP 0.1f
#define UH 58
#define UW 58

typedef float f32x4 __attribute__((ext_vector_type(4)));  // native vec: OK for nontemporal builtins

// One block. Bitmask dilation: row i of drop -> 64-bit word; 7x7 max-dilate =
// OR of 7 shifted words (row) then OR of <=7 rows (col). keep-count via popcount.
__global__ __launch_bounds__(1024) void dropblock_mask_kernel(
    const float* __restrict__ u, float* __restrict__ m)
{
    __shared__ unsigned long long sD[64];    // per-row drop bits (rows >=58 zero)
    __shared__ unsigned long long sR[64];    // row-dilated
    __shared__ unsigned long long sDil[64];  // fully dilated
    __shared__ float sscale;

    const int tid  = threadIdx.x;
    const int wave = tid >> 6;   // 0..15
    const int lane = tid & 63;

    // Phase 1: wave w builds rows w, w+16, w+32, w+48 via ballot
    for (int i = wave; i < 64; i += 16) {
        bool d = false;
        if (i < UH && lane < UW) d = (u[i * UW + lane] < DROPP);
        unsigned long long D = __ballot(d);
        if (lane == 0) sD[i] = D;
    }
    __syncthreads();

    // Phase 2: wave 0, lane i: row dilation (6 shifts+ORs)
    if (wave == 0) {
        unsigned long long D = sD[lane];
        unsigned long long R = D;
        #pragma unroll
        for (int s = 1; s <= 6; ++s) R |= (D << s);
        sR[lane] = R;
    }
    __syncthreads();

    // Phase 3: wave 0, lane y: column dilation + popcount + wave-reduce sum
    if (wave == 0) {
        const int y = lane;
        const int i0 = (y - 6 > 0) ? (y - 6) : 0;
        const int i1 = (y < UH - 1) ? y : (UH - 1);
        unsigned long long dil = 0ull;
        for (int i = i0; i <= i1; ++i) dil |= sR[i];
        sDil[y] = dil;
        float kept = (float)(64 - __popcll(dil));
        #pragma unroll
        for (int off = 32; off >= 1; off >>= 1)
            kept += __shfl_down(kept, off, 64);
        if (lane == 0) sscale = 4096.0f / kept;
    }
    __syncthreads();

    // Phase 4: all 1024 threads emit m as one float4 each (coalesced)
    const float s = sscale;
    const unsigned long long dil = sDil[(tid >> 4) & 63]; // y = (4*tid)>>6
    const int xb = (tid * 4) & 63;                        // <= 60, same word
    f32x4 mv;
    mv.x = ((dil >> (xb + 0)) & 1ull) ? 0.0f : s;
    mv.y = ((dil >> (xb + 1)) & 1ull) ? 0.0f : s;
    mv.z = ((dil >> (xb + 2)) & 1ull) ? 0.0f : s;
    mv.w = ((dil >> (xb + 3)) & 1ull) ? 0.0f : s;
    ((f32x4*)m)[tid] = mv;
}

// HBM-bound streaming multiply. nt hints: x/out are 512 MiB total, >> L2.
__global__ __launch_bounds__(256) void dropblock_apply_kernel(
    const f32x4* __restrict__ x, const f32x4* __restrict__ m4,
    f32x4* __restrict__ out)
{
    const int gid = blockIdx.x * 256 + threadIdx.x;
    const f32x4 xv = __builtin_nontemporal_load(&x[gid]);
    const f32x4 mv = m4[gid & 1023];   // 16 KiB plane, L1/L2-resident
    f32x4 ov = xv * mv;
    __builtin_nontemporal_store(ov, &out[gid]);
}

extern "C" void kernel_launch(void* const* d_in, const int* in_sizes, int n_in,
                              void* d_out, int out_size, void* d_ws, size_t ws_size,
                              hipStream_t stream) {
    const float* x = (const float*)d_in[0];   // [64,256,64,64] fp32
    const float* u = (const float*)d_in[1];   // [58,58] fp32
    float* out = (float*)d_out;
    float* m   = (float*)d_ws;                // 4096 floats scratch

    dropblock_mask_kernel<<<1, 1024, 0, stream>>>(u, m);

    const int total4 = out_size / 4;          // 16,777,216 float4s
    dropblock_apply_kernel<<<total4 / 256, 256, 0, stream>>>(
        (const f32x4*)x, (const f32x4*)m, (f32x4*)out);
}